// Round 12
// baseline (485.143 us; speedup 1.0000x reference)
//
#include <hip/hip_runtime.h>
#include <hip/hip_bf16.h>
#include <math.h>

// Problem constants
#define BB 16
#define NP 150
#define NN 151          // N = Np + 1
#define DD 256
#define HH 8
#define HD 32
#define FFN_ 1024
#define PE_LEN 20200
#define ROWS (BB*NN)    // 2416
#define MPAD 2432       // ROWS padded to 32
#define PE_PAD 20224    // PE_LEN padded to 32

// r5: np ref emulates bf16 matmuls (bf16 operands, f32 acc, bf16 outputs).
// r8: MFMA GEMMs. r11: LDS-staged score dots. r12: (a) GEMM+LN fused for the
// four Nc=256 GEMMs (identical per-tile MFMA order, identical LN reduction
// order); (b) L0 Q/KV gemms merged, pack folded into build launch (18->12
// dispatches); (c) attention block swizzle b=blk&15 so each batch's 151
// blocks share an XCD (pekv L2 locality) — pure permutation.
// Index semantics: pe0 idx = 10100; rel-bucket clips -> 100 / 20100.

typedef __attribute__((ext_vector_type(8))) short short8;   // 8 bf16 = 4 VGPR
typedef __attribute__((ext_vector_type(4))) float f32x4;

__device__ __forceinline__ float r16(float x) {
    return __bfloat162float(__float2bfloat16(x));   // RNE bf16 grid
}
__device__ __forceinline__ float us2f(unsigned short u) {
    return __uint_as_float((unsigned)u << 16);      // bf16 bits -> f32
}
__device__ __forceinline__ unsigned short f2us(float x) {
    __hip_bfloat16 h = __float2bfloat16(x);
    return *reinterpret_cast<unsigned short*>(&h);  // RNE bf16 bits
}

// ---------------------------------------------------------------------------
// build_x (+ fused weight packs on trailing blocks).
// build: x[b,0,:]=latent; x[b,n,:]= [sin(mz/term), cos(mz/term)] + inten*int_w
// (term f64 -> f32 cast, f64 divide, f64 sin/cos). Writes f32 x, bf16 xb,
// fused xqb = bf16(x + pe[10100]).
// ---------------------------------------------------------------------------
#define PACK_BLOCKS 1024
__global__ __launch_bounds__(256) void buildpack_kernel(
    const float* __restrict__ spectra, const float* __restrict__ latent,
    const float* __restrict__ int_w, const float* __restrict__ pe,
    float* __restrict__ x, __hip_bfloat16* __restrict__ xb,
    __hip_bfloat16* __restrict__ xqb,
    float* __restrict__ masses, float* __restrict__ maskf,
    const float* __restrict__ in_w,  __hip_bfloat16* __restrict__ inw_p,
    const float* __restrict__ out_w, __hip_bfloat16* __restrict__ outw_p,
    const float* __restrict__ l1_w,  __hip_bfloat16* __restrict__ l1w_p,
    const float* __restrict__ l2_w,  __hip_bfloat16* __restrict__ l2w_p,
    __hip_bfloat16* __restrict__ pe_p)
{
    int tid = threadIdx.x;
    if (blockIdx.x < ROWS) {
        int bn = blockIdx.x;            // b*NN + n
        int b = bn / NN, n = bn % NN;
        float val;
        if (n == 0) {
            val = latent[tid];
            if (tid == 0) { masses[bn] = 0.0f; maskf[bn] = 0.0f; }
        } else {
            float mz = spectra[(b*NP + n - 1)*2 + 0];
            float it = spectra[(b*NP + n - 1)*2 + 1];
            int i = (tid < 128) ? tid : tid - 128;
            const double base_d = 0.001 / (2.0 * 3.141592653589793);
            double term_d = base_d * pow(1.0e7, (double)i / 127.0);
            float tf = (float)term_d;                   // .astype(np.float32)
            double arg = (double)mz / (double)tf;
            double sv = (tid < 128) ? sin(arg) : cos(arg);
            val = (float)sv + it * int_w[tid];
            if (tid == 0) {
                masses[bn] = mz;
                maskf[bn] = ((mz + it) == 0.0f) ? 1.0f : 0.0f;
            }
        }
        x[bn*DD + tid] = val;
        xb[bn*DD + tid] = __float2bfloat16(val);
        xqb[bn*DD + tid] = __float2bfloat16(val + pe[10100*DD + tid]);
    } else {
        long long base = (long long)(blockIdx.x - ROWS) * 256 + tid;
        const long long stride = (long long)PACK_BLOCKS * 256;
        for (long long i = base; i < (long long)PE_PAD*DD; i += stride)
            pe_p[i] = __float2bfloat16(i < (long long)PE_LEN*DD ? pe[i] : 0.0f);
        for (long long i = base; i < 2LL*768*DD; i += stride)
            inw_p[i] = __float2bfloat16(in_w[i]);
        for (long long i = base; i < 2LL*DD*DD; i += stride)
            outw_p[i] = __float2bfloat16(out_w[i]);
        for (long long i = base; i < 2LL*FFN_*DD; i += stride)
            l1w_p[i] = __float2bfloat16(l1_w[i]);
        for (long long i = base; i < 2LL*DD*FFN_; i += stride)
            l2w_p[i] = __float2bfloat16(l2_w[i]);
    }
}

// ---------------------------------------------------------------------------
// MFMA GEMM: C[M,Nc] = A(bf16) @ W(bf16)^T, f32 acc, epilogue
// r16(r16(acc)+r16(bias)). One wave per 32x32 tile.
// ---------------------------------------------------------------------------
template<typename CT>
__global__ __launch_bounds__(256) void gemm_mfma(
    const __hip_bfloat16* __restrict__ A, const __hip_bfloat16* __restrict__ W,
    const float* __restrict__ bias, CT* __restrict__ C,
    int M, int Nc, int K, int ldc, int relu)
{
    int wave = threadIdx.x >> 6;
    int lane = threadIdx.x & 63;
    int NT = Nc >> 5;
    int MT = (M + 31) >> 5;
    int id = blockIdx.x * 4 + wave;
    if (id >= MT * NT) return;
    int mt = id / NT, nt = id % NT;
    int m0 = mt * 32, n0 = nt * 32;
    int rl = lane & 15, q8 = (lane >> 4) * 8;

    const short8* Ap0 = (const short8*)(A + (size_t)(m0 + rl)*K + q8);
    const short8* Ap1 = (const short8*)(A + (size_t)(m0 + 16 + rl)*K + q8);
    const short8* Wp0 = (const short8*)(W + (size_t)(n0 + rl)*K + q8);
    const short8* Wp1 = (const short8*)(W + (size_t)(n0 + 16 + rl)*K + q8);

    f32x4 acc00 = {0,0,0,0}, acc01 = {0,0,0,0};
    f32x4 acc10 = {0,0,0,0}, acc11 = {0,0,0,0};
    int steps = K >> 5;
    for (int s = 0; s < steps; ++s) {
        short8 a0 = Ap0[s*4];
        short8 a1 = Ap1[s*4];
        short8 b0 = Wp0[s*4];
        short8 b1 = Wp1[s*4];
        acc00 = __builtin_amdgcn_mfma_f32_16x16x32_bf16(a0, b0, acc00, 0, 0, 0);
        acc01 = __builtin_amdgcn_mfma_f32_16x16x32_bf16(a0, b1, acc01, 0, 0, 0);
        acc10 = __builtin_amdgcn_mfma_f32_16x16x32_bf16(a1, b0, acc10, 0, 0, 0);
        acc11 = __builtin_amdgcn_mfma_f32_16x16x32_bf16(a1, b1, acc11, 0, 0, 0);
    }

    int rbase = (lane >> 4) * 4;
    #pragma unroll
    for (int sm = 0; sm < 2; ++sm) {
        #pragma unroll
        for (int sn = 0; sn < 2; ++sn) {
            f32x4 a = (sm == 0) ? (sn == 0 ? acc00 : acc01)
                                : (sn == 0 ? acc10 : acc11);
            int gc = n0 + sn*16 + rl;
            float bv = bias ? r16(bias[gc]) : 0.0f;
            #pragma unroll
            for (int rg = 0; rg < 4; ++rg) {
                int gr = m0 + sm*16 + rbase + rg;
                if (gr < M) {
                    float val = r16(a[rg]);
                    if (bias) val = r16(val + bv);
                    if (relu) val = fmaxf(val, 0.0f);
                    C[(size_t)gr*ldc + gc] = (CT)val;
                }
            }
        }
    }
}

// ---------------------------------------------------------------------------
// L0 fused Q + KV projection: 24 column tiles per M-tile; nt<8 -> Q (A=xqb,
// C=qb ldc 256), else KV (A=xb, C=kvb ldc 512). Per-tile math identical to
// gemm_mfma.
// ---------------------------------------------------------------------------
__global__ __launch_bounds__(256) void gemm_qkv0(
    const __hip_bfloat16* __restrict__ xqb, const __hip_bfloat16* __restrict__ xb,
    const __hip_bfloat16* __restrict__ inw_p, const float* __restrict__ in_b,
    __hip_bfloat16* __restrict__ qb, __hip_bfloat16* __restrict__ kvb, int M)
{
    int wave = threadIdx.x >> 6;
    int lane = threadIdx.x & 63;
    int MT = (M + 31) >> 5;
    int id = blockIdx.x * 4 + wave;
    if (id >= MT * 24) return;
    int mt = id / 24, ntt = id % 24;
    bool isQ = (ntt < 8);
    const __hip_bfloat16* A = isQ ? xqb : xb;
    const __hip_bfloat16* W = inw_p + (isQ ? (size_t)ntt*32*DD
                                           : (size_t)(256 + (ntt-8)*32)*DD);
    const float* bias = in_b + (isQ ? ntt*32 : 256 + (ntt-8)*32);
    __hip_bfloat16* C = isQ ? qb : kvb;
    int ldc = isQ ? 256 : 512;
    int cbase = isQ ? ntt*32 : (ntt-8)*32;
    int m0 = mt * 32;
    int rl = lane & 15, q8 = (lane >> 4) * 8;
    const int K = DD;

    const short8* Ap0 = (const short8*)(A + (size_t)(m0 + rl)*K + q8);
    const short8* Ap1 = (const short8*)(A + (size_t)(m0 + 16 + rl)*K + q8);
    const short8* Wp0 = (const short8*)(W + (size_t)(rl)*K + q8);
    const short8* Wp1 = (const short8*)(W + (size_t)(16 + rl)*K + q8);

    f32x4 acc00 = {0,0,0,0}, acc01 = {0,0,0,0};
    f32x4 acc10 = {0,0,0,0}, acc11 = {0,0,0,0};
    for (int s = 0; s < K/32; ++s) {
        short8 a0 = Ap0[s*4];
        short8 a1 = Ap1[s*4];
        short8 b0 = Wp0[s*4];
        short8 b1 = Wp1[s*4];
        acc00 = __builtin_amdgcn_mfma_f32_16x16x32_bf16(a0, b0, acc00, 0, 0, 0);
        acc01 = __builtin_amdgcn_mfma_f32_16x16x32_bf16(a0, b1, acc01, 0, 0, 0);
        acc10 = __builtin_amdgcn_mfma_f32_16x16x32_bf16(a1, b0, acc10, 0, 0, 0);
        acc11 = __builtin_amdgcn_mfma_f32_16x16x32_bf16(a1, b1, acc11, 0, 0, 0);
    }

    int rbase = (lane >> 4) * 4;
    #pragma unroll
    for (int sm = 0; sm < 2; ++sm) {
        #pragma unroll
        for (int sn = 0; sn < 2; ++sn) {
            f32x4 a = (sm == 0) ? (sn == 0 ? acc00 : acc01)
                                : (sn == 0 ? acc10 : acc11);
            int gc = cbase + sn*16 + rl;
            float bv = r16(bias[sn*16 + rl]);
            #pragma unroll
            for (int rg = 0; rg < 4; ++rg) {
                int gr = m0 + sm*16 + rbase + rg;
                if (gr < M) {
                    float val = r16(a[rg]);
                    val = r16(val + bv);
                    C[(size_t)gr*ldc + gc] = (__hip_bfloat16)val;
                }
            }
        }
    }
}

// ---------------------------------------------------------------------------
// Fused GEMM (Nc=256) + residual add + LayerNorm. One block per 32-row strip;
// wave w computes column tiles 2w, 2w+1 (identical per-tile MFMA order and
// epilogue as gemm_mfma), strip staged in LDS, then the EXACT add_ln
// reduction per row. TO_OUT: final write to d_out (f32 only).
// ---------------------------------------------------------------------------
template<bool TO_OUT>
__global__ __launch_bounds__(256) void gemm_ln(
    const __hip_bfloat16* __restrict__ A, const __hip_bfloat16* __restrict__ W,
    const float* __restrict__ bias,
    const float* __restrict__ xres, const float* __restrict__ g,
    const float* __restrict__ bb,
    float* __restrict__ xout, __hip_bfloat16* __restrict__ xbout,
    int M, int K)
{
    __shared__ float Cs[32][DD];    // 32 KB
    __shared__ float red[4];
    int tid = threadIdx.x;
    int wave = tid >> 6, lane = tid & 63;
    int m0 = blockIdx.x * 32;
    int rl = lane & 15, q8 = (lane >> 4) * 8;
    int n0 = wave * 64;

    const short8* Ap0 = (const short8*)(A + (size_t)(m0 + rl)*K + q8);
    const short8* Ap1 = (const short8*)(A + (size_t)(m0 + 16 + rl)*K + q8);
    const short8* Wp0 = (const short8*)(W + (size_t)(n0 + rl)*K + q8);
    const short8* Wp1 = (const short8*)(W + (size_t)(n0 + 16 + rl)*K + q8);
    const short8* Wp2 = (const short8*)(W + (size_t)(n0 + 32 + rl)*K + q8);
    const short8* Wp3 = (const short8*)(W + (size_t)(n0 + 48 + rl)*K + q8);

    f32x4 acc[2][2][2] = {};        // [ctile][sm][sn]
    int steps = K >> 5;
    for (int s = 0; s < steps; ++s) {
        short8 a0 = Ap0[s*4];
        short8 a1 = Ap1[s*4];
        short8 b00 = Wp0[s*4];
        short8 b01 = Wp1[s*4];
        short8 b10 = Wp2[s*4];
        short8 b11 = Wp3[s*4];
        acc[0][0][0] = __builtin_amdgcn_mfma_f32_16x16x32_bf16(a0, b00, acc[0][0][0], 0, 0, 0);
        acc[0][0][1] = __builtin_amdgcn_mfma_f32_16x16x32_bf16(a0, b01, acc[0][0][1], 0, 0, 0);
        acc[0][1][0] = __builtin_amdgcn_mfma_f32_16x16x32_bf16(a1, b00, acc[0][1][0], 0, 0, 0);
        acc[0][1][1] = __builtin_amdgcn_mfma_f32_16x16x32_bf16(a1, b01, acc[0][1][1], 0, 0, 0);
        acc[1][0][0] = __builtin_amdgcn_mfma_f32_16x16x32_bf16(a0, b10, acc[1][0][0], 0, 0, 0);
        acc[1][0][1] = __builtin_amdgcn_mfma_f32_16x16x32_bf16(a0, b11, acc[1][0][1], 0, 0, 0);
        acc[1][1][0] = __builtin_amdgcn_mfma_f32_16x16x32_bf16(a1, b10, acc[1][1][0], 0, 0, 0);
        acc[1][1][1] = __builtin_amdgcn_mfma_f32_16x16x32_bf16(a1, b11, acc[1][1][1], 0, 0, 0);
    }

    int rbase = (lane >> 4) * 4;
    #pragma unroll
    for (int c = 0; c < 2; ++c) {
        #pragma unroll
        for (int sm = 0; sm < 2; ++sm) {
            #pragma unroll
            for (int sn = 0; sn < 2; ++sn) {
                f32x4 a = acc[c][sm][sn];
                int col = n0 + c*32 + sn*16 + rl;
                float bv = r16(bias[col]);
                #pragma unroll
                for (int rg = 0; rg < 4; ++rg) {
                    int rloc = sm*16 + rbase + rg;
                    float val = r16(a[rg]);          // bf16 matmul output
                    val = r16(val + bv);             // bf16 bias add
                    Cs[rloc][col] = val;
                }
            }
        }
    }
    __syncthreads();

    int nrows = M - m0; if (nrows > 32) nrows = 32;
    for (int r = 0; r < nrows; ++r) {
        int row = m0 + r;
        float v = xres[(size_t)row*DD + tid] + Cs[r][tid];
        float s = v;
        #pragma unroll
        for (int off = 32; off; off >>= 1) s += __shfl_xor(s, off);
        if ((tid & 63) == 0) red[tid >> 6] = s;
        __syncthreads();
        float mu = (red[0] + red[1] + red[2] + red[3]) * (1.0f/256.0f);
        __syncthreads();
        float d = v - mu;
        float s2 = d*d;
        #pragma unroll
        for (int off = 32; off; off >>= 1) s2 += __shfl_xor(s2, off);
        if ((tid & 63) == 0) red[tid >> 6] = s2;
        __syncthreads();
        float var = (red[0] + red[1] + red[2] + red[3]) * (1.0f/256.0f);
        float out = d * (1.0f / sqrtf(var + 1e-5f)) * g[tid] + bb[tid];
        xout[(size_t)row*DD + tid] = out;
        if (!TO_OUT) xbout[(size_t)row*DD + tid] = __float2bfloat16(out);
        __syncthreads();    // protect red before next row
    }
}

// ---------------------------------------------------------------------------
// Fused attention, one block per (b,i) with b = blk&15 (XCD locality: all
// blocks of a batch share an XCD under round-robin dispatch). 256 threads.
// Phase A: LDS-staged bf16 K-operand tiles + one thread per (j,h) sequential
// dot. Phase B: pipelined per-dim gather, single ascending-j fma chain.
// pekv rows (bf16): [PEK(256)|PEV(256)], stride 512.
// ---------------------------------------------------------------------------
#define KSTRIDE 260
template<bool USE_PE, int QS, int KS, int VS>
__global__ __launch_bounds__(256) void attn_kernel(
    const __hip_bfloat16* __restrict__ qp,
    const __hip_bfloat16* __restrict__ kp,
    const __hip_bfloat16* __restrict__ vp,
    const __hip_bfloat16* __restrict__ pekv,
    const float* __restrict__ masses, const float* __restrict__ maskf,
    __hip_bfloat16* __restrict__ yb)
{
    int b = blockIdx.x & 15;        // XCD-locality swizzle (pure permutation)
    int i = blockIdx.x >> 4;
    int tid = threadIdx.x;
    int lane = tid & 31, grp = tid >> 5;    // grp == head

    __shared__ unsigned short Ks[32*KSTRIDE];
    __shared__ unsigned short qs16[DD];
    __shared__ float sc[HH][160];
    __shared__ float msh[NN + 1];
    __shared__ int tj[NN + 1];

    qs16[tid] = ((const unsigned short*)qp)[(size_t)(b*NN + i)*QS + tid];
    if (tid < NN) {
        msh[tid] = maskf[b*NN + tid];
        if (USE_PE) {
            double m = (double)masses[b*NN + tid] - (double)masses[b*NN + i];
            m = fmin(fmax(m, -100.0), 100.0);
            tj[tid] = (int)(((m + 1.0) + 100.0) / 0.01);  // f64: clips 100/20100
        }
    }
    __syncthreads();

    const float scale = 0.17677669529663687f;   // 1/sqrt(32)
    const unsigned short* kb16 = (const unsigned short*)kp + (size_t)(b*NN)*KS + tid;
    const __hip_bfloat16* kbf  = kp + (size_t)(b*NN)*KS + tid;
    const __hip_bfloat16* vbase = vp + (size_t)(b*NN)*VS + tid;
    const __hip_bfloat16* pk = pekv + tid;          // K-half column
    const __hip_bfloat16* pv = pekv + 256 + tid;    // V-half column

    // ---- Phase A: scores via LDS-staged tiles ----
    for (int t = 0; t < 5; ++t) {
        int j0 = t*32;
        #pragma unroll
        for (int c = 0; c < 2; ++c) {
            int rb = c*16;
            if (USE_PE) {
                float kr[16], pr[16];
                #pragma unroll
                for (int u = 0; u < 16; ++u) {
                    int j = j0 + rb + u;
                    if (j < NN) {
                        kr[u] = __bfloat162float(kbf[(size_t)j*KS]);
                        pr[u] = __bfloat162float(pk[(size_t)tj[j]*512]);
                    }
                }
                #pragma unroll
                for (int u = 0; u < 16; ++u) {
                    int j = j0 + rb + u;
                    if (j < NN) Ks[(rb+u)*KSTRIDE + tid] = f2us(kr[u] + pr[u]);
                }
            } else {
                unsigned short ur[16];
                #pragma unroll
                for (int u = 0; u < 16; ++u) {
                    int j = j0 + rb + u;
                    if (j < NN) ur[u] = kb16[(size_t)j*KS];
                }
                #pragma unroll
                for (int u = 0; u < 16; ++u) {
                    int j = j0 + rb + u;
                    if (j < NN) Ks[(rb+u)*KSTRIDE + tid] = ur[u];
                }
            }
        }
        __syncthreads();
        {
            int jl = lane, h = grp;
            int j = j0 + jl;
            if (j < NN) {
                const unsigned short* krow = &Ks[jl*KSTRIDE + h*32];
                const unsigned short* qrow = &qs16[h*32];
                float acc = 0.0f;
                #pragma unroll
                for (int d = 0; d < 32; ++d)
                    acc = fmaf(us2f(qrow[d]), us2f(krow[d]), acc);
                float s = acc * scale;
                if (msh[j] != 0.0f) s = -1e9f;
                sc[h][j] = s;
            }
        }
        __syncthreads();
    }

    // ---- softmax per head, f32, within-wave ----
    {
        int h = grp;
        float mx = -INFINITY;
        for (int j = lane; j < NN; j += 32) mx = fmaxf(mx, sc[h][j]);
        #pragma unroll
        for (int off = 16; off; off >>= 1) mx = fmaxf(mx, __shfl_xor(mx, off, 32));
        float sum = 0.0f;
        for (int j = lane; j < NN; j += 32) {
            float e = expf(sc[h][j] - mx);
            sc[h][j] = e;
            sum += e;
        }
        #pragma unroll
        for (int off = 16; off; off >>= 1) sum += __shfl_xor(sum, off, 32);
        float inv = 1.0f / sum;
        for (int j = lane; j < NN; j += 32) sc[h][j] = r16(sc[h][j] * inv); // bf16(a)
    }
    __builtin_amdgcn_wave_barrier();    // in-wave DS order fence

    // ---- Phase B: y = sum_j a[h][j] * bf16(V[j] (+ PEV[tj])), pipelined ----
    {
        int h = grp;
        float acc = 0.0f;
        float vraw[8], praw[8];
        #pragma unroll
        for (int u = 0; u < 8; ++u) {
            vraw[u] = __bfloat162float(vbase[(size_t)u * VS]);
            if (USE_PE) praw[u] = __bfloat162float(pv[(size_t)tj[u] * 512]);
        }
        for (int t = 0; t < 19; ++t) {
            int j0 = t*8;
            int cnt = NN - j0; if (cnt > 8) cnt = 8;
            float vn[8], pn[8];
            if (t < 18) {
                int nb = j0 + 8;
                int ncnt = NN - nb; if (ncnt > 8) ncnt = 8;
                #pragma unroll
                for (int u = 0; u < 8; ++u) {
                    if (u < ncnt) {
                        vn[u] = __bfloat162float(vbase[(size_t)(nb + u) * VS]);
                        if (USE_PE) pn[u] = __bfloat162float(pv[(size_t)tj[nb + u] * 512]);
                    } else { vn[u] = 0.0f; pn[u] = 0.0f; }
                }
            }
            #pragma unroll
            for (int u = 0; u < 8; ++u) {
                if (u < cnt) {
                    float vv = vraw[u];
                    if (USE_PE) vv = r16(vv + praw[u]);    // bf16(V) operand
                    acc = fmaf(sc[h][j0 + u], vv, acc);
                }
            }
            if (t < 18) {
                #pragma unroll
                for (int u = 0; u < 8; ++u) {
                    vraw[u] = vn[u];
                    if (USE_PE) praw[u] = pn[u];
                }
            }
        }
        yb[(size_t)(b*NN + i)*DD + tid] = __float2bfloat16(acc);
    }
}

// ---------------------------------------------------------------------------
extern "C" void kernel_launch(void* const* d_in, const int* in_sizes, int n_in,
                              void* d_out, int out_size, void* d_ws, size_t ws_size,
                              hipStream_t stream)
{
    const float* spectra = (const float*)d_in[0];
    const float* pe      = (const float*)d_in[1];
    const float* latent  = (const float*)d_in[2];
    const float* int_w   = (const float*)d_in[3];
    const float* in_w    = (const float*)d_in[4];
    const float* in_b    = (const float*)d_in[5];
    const float* out_w   = (const float*)d_in[6];
    const float* out_b   = (const float*)d_in[7];
    const float* l1_w    = (const float*)d_in[8];
    const float* l1_b    = (const float*)d_in[9];
    const float* l2_w    = (const float*)d_in[10];
    const float* l2_b    = (const float*)d_in[11];
    const float* n1_g    = (const float*)d_in[12];
    const float* n1_b    = (const float*)d_in[13];
    const float* n2_g    = (const float*)d_in[14];
    const float* n2_b    = (const float*)d_in[15];

    // ---- workspace layout ----
    float* x      = (float*)d_ws;                 // ROWS*256
    float* masses = x      + ROWS*DD;             // ROWS
    float* maskf  = masses + ROWS;                // ROWS
    __hip_bfloat16* bp = (__hip_bfloat16*)(maskf + ROWS);
    __hip_bfloat16* xb    = bp;  bp += (size_t)MPAD*DD;
    __hip_bfloat16* xqb   = bp;  bp += (size_t)MPAD*DD;
    __hip_bfloat16* qb    = bp;  bp += (size_t)MPAD*DD;
    __hip_bfloat16* kvb   = bp;  bp += (size_t)MPAD*768;
    __hip_bfloat16* yb    = bp;  bp += (size_t)MPAD*DD;
    __hip_bfloat16* f1b   = bp;  bp += (size_t)MPAD*FFN_;
    __hip_bfloat16* pekv  = bp;  bp += (size_t)PE_PAD*512;
    __hip_bfloat16* pe_p  = bp;  bp += (size_t)PE_PAD*DD;
    __hip_bfloat16* inw_p = bp;  bp += (size_t)2*768*DD;
    __hip_bfloat16* outw_p= bp;  bp += (size_t)2*DD*DD;
    __hip_bfloat16* l1w_p = bp;  bp += (size_t)2*FFN_*DD;
    __hip_bfloat16* l2w_p = bp;  bp += (size_t)2*DD*FFN_;

    dim3 blk(256);
    auto GG = [](int M, int Nc){ return dim3((unsigned)((((M+31)>>5)*(Nc>>5) + 3) / 4)); };
    const unsigned STRIPS = (ROWS + 31) / 32;    // 76

    // ---- build_x + all weight packs, one dispatch ----
    buildpack_kernel<<<ROWS + PACK_BLOCKS, blk, 0, stream>>>(
        spectra, latent, int_w, pe, x, xb, xqb, masses, maskf,
        in_w, inw_p, out_w, outw_p, l1_w, l1w_p, l2_w, l2w_p, pe_p);

    // PEK|PEV = bf16(pe) @ bf16([wk0;wv0])^T, stored bf16
    gemm_mfma<__hip_bfloat16><<<GG(PE_LEN, 512), blk, 0, stream>>>(
        pe_p, inw_p + 256*DD, nullptr, pekv, PE_LEN, 512, 256, 512, 0);

    // ---------------- layer 0 ----------------
    gemm_qkv0<<<dim3((STRIPS*24 + 3)/4), blk, 0, stream>>>(
        xqb, xb, inw_p, in_b, qb, kvb, ROWS);
    attn_kernel<true,256,512,512><<<ROWS, blk, 0, stream>>>(
        qb, kvb, kvb + 256, pekv, masses, maskf, yb);
    gemm_ln<false><<<STRIPS, blk, 0, stream>>>(
        yb, outw_p, out_b, x, n1_g, n1_b, x, xb, ROWS, 256);
    gemm_mfma<__hip_bfloat16><<<GG(ROWS, 1024), blk, 0, stream>>>(
        xb, l1w_p, l1_b, f1b, ROWS, 1024, 256, 1024, 1);
    gemm_ln<false><<<STRIPS, blk, 0, stream>>>(
        f1b, l2w_p, l2_b, x, n2_g, n2_b, x, xb, ROWS, 1024);

    // ---------------- layer 1 ----------------
    gemm_mfma<__hip_bfloat16><<<GG(ROWS, 768), blk, 0, stream>>>(
        xb, inw_p + 768*DD, in_b + 768, kvb, ROWS, 768, 256, 768, 0);
    attn_kernel<false,768,768,768><<<ROWS, blk, 0, stream>>>(
        kvb, kvb + 256, kvb + 512, nullptr, masses, maskf, yb);
    gemm_ln<false><<<STRIPS, blk, 0, stream>>>(
        yb, outw_p + 256*DD, out_b + 256, x, n1_g + 256, n1_b + 256, x, xb, ROWS, 256);
    gemm_mfma<__hip_bfloat16><<<GG(ROWS, 1024), blk, 0, stream>>>(
        xb, l1w_p + FFN_*DD, l1_b + 1024, f1b, ROWS, 1024, 256, 1024, 1);
    gemm_ln<true><<<STRIPS, blk, 0, stream>>>(
        f1b, l2w_p + DD*FFN_, l2_b + 256, x, n2_g + 256, n2_b + 256,
        (float*)d_out, nullptr, ROWS, 1024);
}

// Round 13
// 385.877 us; speedup vs baseline: 1.2572x; 1.2572x over previous
//
#include <hip/hip_runtime.h>
#include <hip/hip_bf16.h>
#include <math.h>

// Problem constants
#define BB 16
#define NP 150
#define NN 151          // N = Np + 1
#define DD 256
#define HH 8
#define HD 32
#define FFN_ 1024
#define PE_LEN 20200
#define ROWS (BB*NN)    // 2416
#define MPAD 2432       // ROWS padded to 32
#define PE_PAD 20224    // PE_LEN padded to 32

// r5: np ref emulates bf16 matmuls (bf16 operands, f32 acc, bf16 outputs).
// r8: MFMA GEMMs. r11: LDS-staged score dots (390 us). r12: gemm_ln fusion
// REGRESSED (76-block grid + serialized LN loop, 485 us) — r13 reverts to
// the r11 gemm_mfma + add_ln pair, keeping r12's good parts: buildpack
// merge, gemm_qkv0 merge, attention XCD swizzle (pure permutation).
// Index semantics: pe0 idx = 10100; rel-bucket clips -> 100 / 20100.

typedef __attribute__((ext_vector_type(8))) short short8;   // 8 bf16 = 4 VGPR
typedef __attribute__((ext_vector_type(4))) float f32x4;

__device__ __forceinline__ float r16(float x) {
    return __bfloat162float(__float2bfloat16(x));   // RNE bf16 grid
}
__device__ __forceinline__ float us2f(unsigned short u) {
    return __uint_as_float((unsigned)u << 16);      // bf16 bits -> f32
}
__device__ __forceinline__ unsigned short f2us(float x) {
    __hip_bfloat16 h = __float2bfloat16(x);
    return *reinterpret_cast<unsigned short*>(&h);  // RNE bf16 bits
}

// ---------------------------------------------------------------------------
// build_x (+ fused weight packs on trailing blocks).
// ---------------------------------------------------------------------------
#define PACK_BLOCKS 1024
__global__ __launch_bounds__(256) void buildpack_kernel(
    const float* __restrict__ spectra, const float* __restrict__ latent,
    const float* __restrict__ int_w, const float* __restrict__ pe,
    float* __restrict__ x, __hip_bfloat16* __restrict__ xb,
    __hip_bfloat16* __restrict__ xqb,
    float* __restrict__ masses, float* __restrict__ maskf,
    const float* __restrict__ in_w,  __hip_bfloat16* __restrict__ inw_p,
    const float* __restrict__ out_w, __hip_bfloat16* __restrict__ outw_p,
    const float* __restrict__ l1_w,  __hip_bfloat16* __restrict__ l1w_p,
    const float* __restrict__ l2_w,  __hip_bfloat16* __restrict__ l2w_p,
    __hip_bfloat16* __restrict__ pe_p)
{
    int tid = threadIdx.x;
    if (blockIdx.x < ROWS) {
        int bn = blockIdx.x;            // b*NN + n
        int b = bn / NN, n = bn % NN;
        float val;
        if (n == 0) {
            val = latent[tid];
            if (tid == 0) { masses[bn] = 0.0f; maskf[bn] = 0.0f; }
        } else {
            float mz = spectra[(b*NP + n - 1)*2 + 0];
            float it = spectra[(b*NP + n - 1)*2 + 1];
            int i = (tid < 128) ? tid : tid - 128;
            const double base_d = 0.001 / (2.0 * 3.141592653589793);
            double term_d = base_d * pow(1.0e7, (double)i / 127.0);
            float tf = (float)term_d;                   // .astype(np.float32)
            double arg = (double)mz / (double)tf;
            double sv = (tid < 128) ? sin(arg) : cos(arg);
            val = (float)sv + it * int_w[tid];
            if (tid == 0) {
                masses[bn] = mz;
                maskf[bn] = ((mz + it) == 0.0f) ? 1.0f : 0.0f;
            }
        }
        x[bn*DD + tid] = val;
        xb[bn*DD + tid] = __float2bfloat16(val);
        xqb[bn*DD + tid] = __float2bfloat16(val + pe[10100*DD + tid]);
    } else {
        long long base = (long long)(blockIdx.x - ROWS) * 256 + tid;
        const long long stride = (long long)PACK_BLOCKS * 256;
        for (long long i = base; i < (long long)PE_PAD*DD; i += stride)
            pe_p[i] = __float2bfloat16(i < (long long)PE_LEN*DD ? pe[i] : 0.0f);
        for (long long i = base; i < 2LL*768*DD; i += stride)
            inw_p[i] = __float2bfloat16(in_w[i]);
        for (long long i = base; i < 2LL*DD*DD; i += stride)
            outw_p[i] = __float2bfloat16(out_w[i]);
        for (long long i = base; i < 2LL*FFN_*DD; i += stride)
            l1w_p[i] = __float2bfloat16(l1_w[i]);
        for (long long i = base; i < 2LL*DD*FFN_; i += stride)
            l2w_p[i] = __float2bfloat16(l2_w[i]);
    }
}

// ---------------------------------------------------------------------------
// MFMA GEMM: C[M,Nc] = A(bf16) @ W(bf16)^T, f32 acc, epilogue
// r16(r16(acc)+r16(bias)). One wave per 32x32 tile.
// ---------------------------------------------------------------------------
template<typename CT>
__global__ __launch_bounds__(256) void gemm_mfma(
    const __hip_bfloat16* __restrict__ A, const __hip_bfloat16* __restrict__ W,
    const float* __restrict__ bias, CT* __restrict__ C,
    int M, int Nc, int K, int ldc, int relu)
{
    int wave = threadIdx.x >> 6;
    int lane = threadIdx.x & 63;
    int NT = Nc >> 5;
    int MT = (M + 31) >> 5;
    int id = blockIdx.x * 4 + wave;
    if (id >= MT * NT) return;
    int mt = id / NT, nt = id % NT;
    int m0 = mt * 32, n0 = nt * 32;
    int rl = lane & 15, q8 = (lane >> 4) * 8;

    const short8* Ap0 = (const short8*)(A + (size_t)(m0 + rl)*K + q8);
    const short8* Ap1 = (const short8*)(A + (size_t)(m0 + 16 + rl)*K + q8);
    const short8* Wp0 = (const short8*)(W + (size_t)(n0 + rl)*K + q8);
    const short8* Wp1 = (const short8*)(W + (size_t)(n0 + 16 + rl)*K + q8);

    f32x4 acc00 = {0,0,0,0}, acc01 = {0,0,0,0};
    f32x4 acc10 = {0,0,0,0}, acc11 = {0,0,0,0};
    int steps = K >> 5;
    for (int s = 0; s < steps; ++s) {
        short8 a0 = Ap0[s*4];
        short8 a1 = Ap1[s*4];
        short8 b0 = Wp0[s*4];
        short8 b1 = Wp1[s*4];
        acc00 = __builtin_amdgcn_mfma_f32_16x16x32_bf16(a0, b0, acc00, 0, 0, 0);
        acc01 = __builtin_amdgcn_mfma_f32_16x16x32_bf16(a0, b1, acc01, 0, 0, 0);
        acc10 = __builtin_amdgcn_mfma_f32_16x16x32_bf16(a1, b0, acc10, 0, 0, 0);
        acc11 = __builtin_amdgcn_mfma_f32_16x16x32_bf16(a1, b1, acc11, 0, 0, 0);
    }

    int rbase = (lane >> 4) * 4;
    #pragma unroll
    for (int sm = 0; sm < 2; ++sm) {
        #pragma unroll
        for (int sn = 0; sn < 2; ++sn) {
            f32x4 a = (sm == 0) ? (sn == 0 ? acc00 : acc01)
                                : (sn == 0 ? acc10 : acc11);
            int gc = n0 + sn*16 + rl;
            float bv = bias ? r16(bias[gc]) : 0.0f;
            #pragma unroll
            for (int rg = 0; rg < 4; ++rg) {
                int gr = m0 + sm*16 + rbase + rg;
                if (gr < M) {
                    float val = r16(a[rg]);
                    if (bias) val = r16(val + bv);
                    if (relu) val = fmaxf(val, 0.0f);
                    C[(size_t)gr*ldc + gc] = (CT)val;
                }
            }
        }
    }
}

// ---------------------------------------------------------------------------
// L0 fused Q + KV projection: 24 column tiles per M-tile; nt<8 -> Q (A=xqb,
// C=qb ldc 256), else KV (A=xb, C=kvb ldc 512).
// ---------------------------------------------------------------------------
__global__ __launch_bounds__(256) void gemm_qkv0(
    const __hip_bfloat16* __restrict__ xqb, const __hip_bfloat16* __restrict__ xb,
    const __hip_bfloat16* __restrict__ inw_p, const float* __restrict__ in_b,
    __hip_bfloat16* __restrict__ qb, __hip_bfloat16* __restrict__ kvb, int M)
{
    int wave = threadIdx.x >> 6;
    int lane = threadIdx.x & 63;
    int MT = (M + 31) >> 5;
    int id = blockIdx.x * 4 + wave;
    if (id >= MT * 24) return;
    int mt = id / 24, ntt = id % 24;
    bool isQ = (ntt < 8);
    const __hip_bfloat16* A = isQ ? xqb : xb;
    const __hip_bfloat16* W = inw_p + (isQ ? (size_t)ntt*32*DD
                                           : (size_t)(256 + (ntt-8)*32)*DD);
    const float* bias = in_b + (isQ ? ntt*32 : 256 + (ntt-8)*32);
    __hip_bfloat16* C = isQ ? qb : kvb;
    int ldc = isQ ? 256 : 512;
    int cbase = isQ ? ntt*32 : (ntt-8)*32;
    int m0 = mt * 32;
    int rl = lane & 15, q8 = (lane >> 4) * 8;
    const int K = DD;

    const short8* Ap0 = (const short8*)(A + (size_t)(m0 + rl)*K + q8);
    const short8* Ap1 = (const short8*)(A + (size_t)(m0 + 16 + rl)*K + q8);
    const short8* Wp0 = (const short8*)(W + (size_t)(rl)*K + q8);
    const short8* Wp1 = (const short8*)(W + (size_t)(16 + rl)*K + q8);

    f32x4 acc00 = {0,0,0,0}, acc01 = {0,0,0,0};
    f32x4 acc10 = {0,0,0,0}, acc11 = {0,0,0,0};
    for (int s = 0; s < K/32; ++s) {
        short8 a0 = Ap0[s*4];
        short8 a1 = Ap1[s*4];
        short8 b0 = Wp0[s*4];
        short8 b1 = Wp1[s*4];
        acc00 = __builtin_amdgcn_mfma_f32_16x16x32_bf16(a0, b0, acc00, 0, 0, 0);
        acc01 = __builtin_amdgcn_mfma_f32_16x16x32_bf16(a0, b1, acc01, 0, 0, 0);
        acc10 = __builtin_amdgcn_mfma_f32_16x16x32_bf16(a1, b0, acc10, 0, 0, 0);
        acc11 = __builtin_amdgcn_mfma_f32_16x16x32_bf16(a1, b1, acc11, 0, 0, 0);
    }

    int rbase = (lane >> 4) * 4;
    #pragma unroll
    for (int sm = 0; sm < 2; ++sm) {
        #pragma unroll
        for (int sn = 0; sn < 2; ++sn) {
            f32x4 a = (sm == 0) ? (sn == 0 ? acc00 : acc01)
                                : (sn == 0 ? acc10 : acc11);
            int gc = cbase + sn*16 + rl;
            float bv = r16(bias[sn*16 + rl]);
            #pragma unroll
            for (int rg = 0; rg < 4; ++rg) {
                int gr = m0 + sm*16 + rbase + rg;
                if (gr < M) {
                    float val = r16(a[rg]);
                    val = r16(val + bv);
                    C[(size_t)gr*ldc + gc] = (__hip_bfloat16)val;
                }
            }
        }
    }
}

// ---------------------------------------------------------------------------
// Fused attention, one block per (b,i) with b = blk&15 (XCD locality).
// Phase A: LDS-staged bf16 K-operand tiles + one thread per (j,h) sequential
// dot. Phase B: pipelined per-dim gather, single ascending-j fma chain.
// pekv rows (bf16): [PEK(256)|PEV(256)], stride 512.
// ---------------------------------------------------------------------------
#define KSTRIDE 260
template<bool USE_PE, int QS, int KS, int VS>
__global__ __launch_bounds__(256) void attn_kernel(
    const __hip_bfloat16* __restrict__ qp,
    const __hip_bfloat16* __restrict__ kp,
    const __hip_bfloat16* __restrict__ vp,
    const __hip_bfloat16* __restrict__ pekv,
    const float* __restrict__ masses, const float* __restrict__ maskf,
    __hip_bfloat16* __restrict__ yb)
{
    int b = blockIdx.x & 15;        // XCD-locality swizzle (pure permutation)
    int i = blockIdx.x >> 4;
    int tid = threadIdx.x;
    int lane = tid & 31, grp = tid >> 5;    // grp == head

    __shared__ unsigned short Ks[32*KSTRIDE];
    __shared__ unsigned short qs16[DD];
    __shared__ float sc[HH][160];
    __shared__ float msh[NN + 1];
    __shared__ int tj[NN + 1];

    qs16[tid] = ((const unsigned short*)qp)[(size_t)(b*NN + i)*QS + tid];
    if (tid < NN) {
        msh[tid] = maskf[b*NN + tid];
        if (USE_PE) {
            double m = (double)masses[b*NN + tid] - (double)masses[b*NN + i];
            m = fmin(fmax(m, -100.0), 100.0);
            tj[tid] = (int)(((m + 1.0) + 100.0) / 0.01);  // f64: clips 100/20100
        }
    }
    __syncthreads();

    const float scale = 0.17677669529663687f;   // 1/sqrt(32)
    const unsigned short* kb16 = (const unsigned short*)kp + (size_t)(b*NN)*KS + tid;
    const __hip_bfloat16* kbf  = kp + (size_t)(b*NN)*KS + tid;
    const __hip_bfloat16* vbase = vp + (size_t)(b*NN)*VS + tid;
    const __hip_bfloat16* pk = pekv + tid;          // K-half column
    const __hip_bfloat16* pv = pekv + 256 + tid;    // V-half column

    // ---- Phase A: scores via LDS-staged tiles ----
    for (int t = 0; t < 5; ++t) {
        int j0 = t*32;
        #pragma unroll
        for (int c = 0; c < 2; ++c) {
            int rb = c*16;
            if (USE_PE) {
                float kr[16], pr[16];
                #pragma unroll
                for (int u = 0; u < 16; ++u) {
                    int j = j0 + rb + u;
                    if (j < NN) {
                        kr[u] = __bfloat162float(kbf[(size_t)j*KS]);
                        pr[u] = __bfloat162float(pk[(size_t)tj[j]*512]);
                    }
                }
                #pragma unroll
                for (int u = 0; u < 16; ++u) {
                    int j = j0 + rb + u;
                    if (j < NN) Ks[(rb+u)*KSTRIDE + tid] = f2us(kr[u] + pr[u]);
                }
            } else {
                unsigned short ur[16];
                #pragma unroll
                for (int u = 0; u < 16; ++u) {
                    int j = j0 + rb + u;
                    if (j < NN) ur[u] = kb16[(size_t)j*KS];
                }
                #pragma unroll
                for (int u = 0; u < 16; ++u) {
                    int j = j0 + rb + u;
                    if (j < NN) Ks[(rb+u)*KSTRIDE + tid] = ur[u];
                }
            }
        }
        __syncthreads();
        {
            int jl = lane, h = grp;
            int j = j0 + jl;
            if (j < NN) {
                const unsigned short* krow = &Ks[jl*KSTRIDE + h*32];
                const unsigned short* qrow = &qs16[h*32];
                float acc = 0.0f;
                #pragma unroll
                for (int d = 0; d < 32; ++d)
                    acc = fmaf(us2f(qrow[d]), us2f(krow[d]), acc);
                float s = acc * scale;
                if (msh[j] != 0.0f) s = -1e9f;
                sc[h][j] = s;
            }
        }
        __syncthreads();
    }

    // ---- softmax per head, f32, within-wave ----
    {
        int h = grp;
        float mx = -INFINITY;
        for (int j = lane; j < NN; j += 32) mx = fmaxf(mx, sc[h][j]);
        #pragma unroll
        for (int off = 16; off; off >>= 1) mx = fmaxf(mx, __shfl_xor(mx, off, 32));
        float sum = 0.0f;
        for (int j = lane; j < NN; j += 32) {
            float e = expf(sc[h][j] - mx);
            sc[h][j] = e;
            sum += e;
        }
        #pragma unroll
        for (int off = 16; off; off >>= 1) sum += __shfl_xor(sum, off, 32);
        float inv = 1.0f / sum;
        for (int j = lane; j < NN; j += 32) sc[h][j] = r16(sc[h][j] * inv); // bf16(a)
    }
    __builtin_amdgcn_wave_barrier();    // in-wave DS order fence

    // ---- Phase B: y = sum_j a[h][j] * bf16(V[j] (+ PEV[tj])), pipelined ----
    {
        int h = grp;
        float acc = 0.0f;
        float vraw[8], praw[8];
        #pragma unroll
        for (int u = 0; u < 8; ++u) {
            vraw[u] = __bfloat162float(vbase[(size_t)u * VS]);
            if (USE_PE) praw[u] = __bfloat162float(pv[(size_t)tj[u] * 512]);
        }
        for (int t = 0; t < 19; ++t) {
            int j0 = t*8;
            int cnt = NN - j0; if (cnt > 8) cnt = 8;
            float vn[8], pn[8];
            if (t < 18) {
                int nb = j0 + 8;
                int ncnt = NN - nb; if (ncnt > 8) ncnt = 8;
                #pragma unroll
                for (int u = 0; u < 8; ++u) {
                    if (u < ncnt) {
                        vn[u] = __bfloat162float(vbase[(size_t)(nb + u) * VS]);
                        if (USE_PE) pn[u] = __bfloat162float(pv[(size_t)tj[nb + u] * 512]);
                    } else { vn[u] = 0.0f; pn[u] = 0.0f; }
                }
            }
            #pragma unroll
            for (int u = 0; u < 8; ++u) {
                if (u < cnt) {
                    float vv = vraw[u];
                    if (USE_PE) vv = r16(vv + praw[u]);    // bf16(V) operand
                    acc = fmaf(sc[h][j0 + u], vv, acc);
                }
            }
            if (t < 18) {
                #pragma unroll
                for (int u = 0; u < 8; ++u) {
                    vraw[u] = vn[u];
                    if (USE_PE) praw[u] = pn[u];
                }
            }
        }
        yb[(size_t)(b*NN + i)*DD + tid] = __float2bfloat16(acc);
    }
}

// ---------------------------------------------------------------------------
// add + layernorm, one block per row (f32). Optionally writes bf16 shadow.
// ---------------------------------------------------------------------------
template<bool WRITE_B>
__global__ __launch_bounds__(256) void add_ln_kernel(
    const float* __restrict__ xin, const float* __restrict__ res,
    const float* __restrict__ g, const float* __restrict__ bb,
    float* __restrict__ xout, __hip_bfloat16* __restrict__ xbout)
{
    int r = blockIdx.x; int tid = threadIdx.x;
    float v = xin[r*DD + tid] + res[r*DD + tid];
    __shared__ float red[4];
    float s = v;
    #pragma unroll
    for (int off = 32; off; off >>= 1) s += __shfl_xor(s, off);
    if ((tid & 63) == 0) red[tid >> 6] = s;
    __syncthreads();
    float mu = (red[0] + red[1] + red[2] + red[3]) * (1.0f/256.0f);
    __syncthreads();
    float d = v - mu;
    float s2 = d*d;
    #pragma unroll
    for (int off = 32; off; off >>= 1) s2 += __shfl_xor(s2, off);
    if ((tid & 63) == 0) red[tid >> 6] = s2;
    __syncthreads();
    float var = (red[0] + red[1] + red[2] + red[3]) * (1.0f/256.0f);
    float out = d * (1.0f / sqrtf(var + 1e-5f)) * g[tid] + bb[tid];
    xout[r*DD + tid] = out;
    if (WRITE_B) xbout[r*DD + tid] = __float2bfloat16(out);
}

// ---------------------------------------------------------------------------
extern "C" void kernel_launch(void* const* d_in, const int* in_sizes, int n_in,
                              void* d_out, int out_size, void* d_ws, size_t ws_size,
                              hipStream_t stream)
{
    const float* spectra = (const float*)d_in[0];
    const float* pe      = (const float*)d_in[1];
    const float* latent  = (const float*)d_in[2];
    const float* int_w   = (const float*)d_in[3];
    const float* in_w    = (const float*)d_in[4];
    const float* in_b    = (const float*)d_in[5];
    const float* out_w   = (const float*)d_in[6];
    const float* out_b   = (const float*)d_in[7];
    const float* l1_w    = (const float*)d_in[8];
    const float* l1_b    = (const float*)d_in[9];
    const float* l2_w    = (const float*)d_in[10];
    const float* l2_b    = (const float*)d_in[11];
    const float* n1_g    = (const float*)d_in[12];
    const float* n1_b    = (const float*)d_in[13];
    const float* n2_g    = (const float*)d_in[14];
    const float* n2_b    = (const float*)d_in[15];

    // ---- workspace layout ----
    float* x      = (float*)d_ws;                 // ROWS*256
    float* y2     = x      + ROWS*DD;             // ROWS*256
    float* masses = y2     + ROWS*DD;             // ROWS
    float* maskf  = masses + ROWS;                // ROWS
    __hip_bfloat16* bp = (__hip_bfloat16*)(maskf + ROWS);
    __hip_bfloat16* xb    = bp;  bp += (size_t)MPAD*DD;
    __hip_bfloat16* xqb   = bp;  bp += (size_t)MPAD*DD;
    __hip_bfloat16* qb    = bp;  bp += (size_t)MPAD*DD;
    __hip_bfloat16* kvb   = bp;  bp += (size_t)MPAD*768;
    __hip_bfloat16* yb    = bp;  bp += (size_t)MPAD*DD;
    __hip_bfloat16* f1b   = bp;  bp += (size_t)MPAD*FFN_;
    __hip_bfloat16* pekv  = bp;  bp += (size_t)PE_PAD*512;
    __hip_bfloat16* pe_p  = bp;  bp += (size_t)PE_PAD*DD;
    __hip_bfloat16* inw_p = bp;  bp += (size_t)2*768*DD;
    __hip_bfloat16* outw_p= bp;  bp += (size_t)2*DD*DD;
    __hip_bfloat16* l1w_p = bp;  bp += (size_t)2*FFN_*DD;
    __hip_bfloat16* l2w_p = bp;  bp += (size_t)2*DD*FFN_;

    dim3 blk(256);
    auto GG = [](int M, int Nc){ return dim3((unsigned)((((M+31)>>5)*(Nc>>5) + 3) / 4)); };
    const unsigned STRIPS = (ROWS + 31) / 32;    // 76

    // ---- build_x + all weight packs, one dispatch ----
    buildpack_kernel<<<ROWS + PACK_BLOCKS, blk, 0, stream>>>(
        spectra, latent, int_w, pe, x, xb, xqb, masses, maskf,
        in_w, inw_p, out_w, outw_p, l1_w, l1w_p, l2_w, l2w_p, pe_p);

    // PEK|PEV = bf16(pe) @ bf16([wk0;wv0])^T, stored bf16
    gemm_mfma<__hip_bfloat16><<<GG(PE_LEN, 512), blk, 0, stream>>>(
        pe_p, inw_p + 256*DD, nullptr, pekv, PE_LEN, 512, 256, 512, 0);

    // ---------------- layer 0 ----------------
    gemm_qkv0<<<dim3((STRIPS*24 + 3)/4), blk, 0, stream>>>(
        xqb, xb, inw_p, in_b, qb, kvb, ROWS);
    attn_kernel<true,256,512,512><<<ROWS, blk, 0, stream>>>(
        qb, kvb, kvb + 256, pekv, masses, maskf, yb);
    gemm_mfma<float><<<GG(ROWS, 256), blk, 0, stream>>>(
        yb, outw_p, out_b, y2, ROWS, 256, 256, 256, 0);
    add_ln_kernel<true><<<ROWS, blk, 0, stream>>>(x, y2, n1_g, n1_b, x, xb);
    gemm_mfma<__hip_bfloat16><<<GG(ROWS, 1024), blk, 0, stream>>>(
        xb, l1w_p, l1_b, f1b, ROWS, 1024, 256, 1024, 1);
    gemm_mfma<float><<<GG(ROWS, 256), blk, 0, stream>>>(
        f1b, l2w_p, l2_b, y2, ROWS, 256, 1024, 256, 0);
    add_ln_kernel<true><<<ROWS, blk, 0, stream>>>(x, y2, n2_g, n2_b, x, xb);

    // ---------------- layer 1 ----------------
    gemm_mfma<__hip_bfloat16><<<GG(ROWS, 768), blk, 0, stream>>>(
        xb, inw_p + 768*DD, in_b + 768, kvb, ROWS, 768, 256, 768, 0);
    attn_kernel<false,768,768,768><<<ROWS, blk, 0, stream>>>(
        kvb, kvb + 256, kvb + 512, nullptr, masses, maskf, yb);
    gemm_mfma<float><<<GG(ROWS, 256), blk, 0, stream>>>(
        yb, outw_p + 256*DD, out_b + 256, y2, ROWS, 256, 256, 256, 0);
    add_ln_kernel<true><<<ROWS, blk, 0, stream>>>(x, y2, n1_g + 256, n1_b + 256, x, xb);
    gemm_mfma<__hip_bfloat16><<<GG(ROWS, 1024), blk, 0, stream>>>(
        xb, l1w_p + FFN_*DD, l1_b + 1024, f1b, ROWS, 1024, 256, 1024, 1);
    gemm_mfma<float><<<GG(ROWS, 256), blk, 0, stream>>>(
        f1b, l2w_p + DD*FFN_, l2_b + 256, y2, ROWS, 256, 1024, 256, 0);
    add_ln_kernel<false><<<ROWS, blk, 0, stream>>>(x, y2, n2_g + 256, n2_b + 256,
                                                   (float*)d_out, nullptr);
}